// Round 18
// baseline (110.263 us; speedup 1.0000x reference)
//
#include <hip/hip_runtime.h>
#include <hip/hip_bf16.h>
#include <math.h>

#define Nn 64
#define Cn 64
#define Tn 64
#define Vn 25
#define Sn 8
#define ICn 8
#define Wn 3
#define WVn 75

typedef __attribute__((ext_vector_type(8))) short s16x8;   // 8 bf16 (4 VGPR)
typedef __attribute__((ext_vector_type(4))) short s16x4;   // 4 bf16 (2 VGPR)
typedef __attribute__((ext_vector_type(4))) float f32x4;   // MFMA acc

#define MFMA16(a, b, c) __builtin_amdgcn_mfma_f32_16x16x32_bf16(a, b, c, 0, 0, 0)

static __device__ inline unsigned short f2bf(float f) {
    __hip_bfloat16 h = __float2bfloat16(f);
    return *reinterpret_cast<unsigned short*>(&h);
}
static __device__ inline float bf2f(unsigned short u) {
    union { unsigned int i; float f; } x;
    x.i = ((unsigned int)u) << 16;
    return x.f;
}

// ---------------------------------------------------------------------------
// K_red (R15 version, 4096 blocks): per (n,c) reductions; n==0 blocks emit
// PRE-FRAGMENTED bf16 weights (owF/ffF).
// ---------------------------------------------------------------------------
__global__ __launch_bounds__(64) void k_red(const float* __restrict__ x,
                                            const float* __restrict__ ga,
                                            const float* __restrict__ ow,
                                            const float* __restrict__ fw,
                                            float* __restrict__ red,
                                            unsigned short* __restrict__ owb,
                                            unsigned short* __restrict__ fwb) {
    const int c = blockIdx.x, n = blockIdx.y;
    const int lane = threadIdx.x;
    if (n == 0) {
        for (int j8 = 0; j8 < 8; ++j8) {
            const int q = c * 512 + j8 * 64 + lane;
            const int j = q & 7, ln = (q >> 3) & 63, fi = q >> 9;
            const int wvq = fi >> 4, ksq = fi & 15;
            owb[q] = f2bf(ow[(wvq * 16 + (ln & 15)) * 512 + ksq * 32 + (ln >> 4) * 8 + j]);
        }
        {
            const int q = c * 64 + lane;
            const int j = q & 7, ln = (q >> 3) & 63, fi = q >> 9;
            const int wvq = fi >> 1, ksq = fi & 1;
            fwb[q] = f2bf(fw[(wvq * 16 + (ln & 15)) * 64 + ksq * 32 + (ln >> 4) * 8 + j]);
        }
    }
    float rs = 0.f, r0 = 0.f, r63 = 0.f, xg = 0.f;
    if (lane < Vn) {
        const float* row = x + ((size_t)(n * Cn + c) * Vn + lane) * Tn;
        float g = 0.f;
        for (int j = 0; j < Vn; ++j) g += ga[lane * Vn + j];
        for (int t = 0; t < Tn; ++t) rs += row[t];
        r0 = row[0];
        r63 = row[Tn - 1];
        xg = rs * g;
    }
    for (int off = 32; off > 0; off >>= 1) {
        rs += __shfl_down(rs, off);
        r0 += __shfl_down(r0, off);
        r63 += __shfl_down(r63, off);
        xg += __shfl_down(xg, off);
    }
    if (lane == 0) {
        float* p = red + (size_t)(n * Cn + c) * 4;
        p[0] = rs; p[1] = r0; p[2] = r63; p[3] = xg;
    }
}

// ---------------------------------------------------------------------------
// K_proj2 (MFMA): q/k conv1x1 -> bf16, layout [n][s][v][t][cc8] (R15 exact).
// ---------------------------------------------------------------------------
__global__ __launch_bounds__(256) void k_proj2(
    const float* __restrict__ x,
    const float* __restrict__ in_w, const float* __restrict__ in_b,
    const float* __restrict__ inup_w, const float* __restrict__ inup_b,
    unsigned short* __restrict__ pk, unsigned short* __restrict__ pq) {
    const int n = blockIdx.x, v = blockIdx.y;
    const int tid = threadIdx.x;
    const int lane = tid & 63, wv = tid >> 6;
    const int r16 = lane & 15, g4 = lane >> 4;

    __shared__ unsigned short WL[128 * 64];
    __shared__ unsigned short XT[64 * 64];
    __shared__ unsigned short CL[64 * 128];
    __shared__ float bias[128];

    if (tid < 128) bias[tid] = (tid < 64) ? in_b[tid] : inup_b[tid - 64];

    for (int idx = tid; idx < 2048; idx += 256) {
        const int o2 = idx >> 4, c4 = idx & 15;
        const float4 d = (o2 < 64)
            ? *(const float4*)(in_w + o2 * 64 + c4 * 4)
            : *(const float4*)(inup_w + (o2 - 64) * 64 + c4 * 4);
        s16x4 p;
        p[0] = (short)f2bf(d.x); p[1] = (short)f2bf(d.y);
        p[2] = (short)f2bf(d.z); p[3] = (short)f2bf(d.w);
        const int ch = c4 >> 1;
        *(s16x4*)&WL[o2 * 64 + (((ch ^ (o2 & 7))) << 3) + (c4 & 1) * 4] = p;
    }
    for (int idx = tid; idx < 1024; idx += 256) {
        const int c = idx >> 4, t4 = idx & 15;
        const float4 d = *(const float4*)(x +
            ((size_t)((n * Cn + c) * Vn + v)) * Tn + t4 * 4);
        const float dv[4] = {d.x, d.y, d.z, d.w};
#pragma unroll
        for (int jj = 0; jj < 4; ++jj) {
            const int t = t4 * 4 + jj;
            XT[t * 64 + (((c >> 3) ^ (t & 7)) << 3) + (c & 7)] = f2bf(dv[jj]);
        }
    }
    __syncthreads();

#pragma unroll
    for (int mi = 0; mi < 2; ++mi) {
        const int mt = wv * 2 + mi;
        const int o2r = mt * 16 + r16;
#pragma unroll
        for (int nt2 = 0; nt2 < 4; ++nt2) {
            const int t = nt2 * 16 + r16;
            f32x4 acc = (f32x4){0.f, 0.f, 0.f, 0.f};
#pragma unroll
            for (int ks = 0; ks < 2; ++ks) {
                const int ch = ks * 4 + g4;
                const s16x8 a = *(const s16x8*)&WL[o2r * 64 + ((ch ^ (o2r & 7)) << 3)];
                const s16x8 b = *(const s16x8*)&XT[t * 64 + ((ch ^ (t & 7)) << 3)];
                acc = MFMA16(a, b, acc);
            }
            const int tcol = nt2 * 16 + r16;
            const int ob = mt * 16 + g4 * 4;
            s16x4 p;
#pragma unroll
            for (int r = 0; r < 4; ++r) p[r] = f2bf(acc[r] + bias[ob + r]);
            const int ch = ob >> 3;
            *(s16x4*)&CL[tcol * 128 + ((ch ^ (tcol & 7)) << 3) + (ob & 7)] = p;
        }
    }
    __syncthreads();

    for (int jj = tid; jj < 1024; jj += 256) {
        const int t = jj & 63, p = jj >> 6;
        const s16x8 d = *(const s16x8*)&CL[t * 128 + ((p ^ (t & 7)) << 3)];
        const int s8 = p & 7;
        unsigned short* dst = (p < 8) ? pk : pq;
        *(s16x8*)(dst + ((((size_t)(n * Sn + s8) * Vn + v) * Tn + t) << 3)) = d;
    }
}

// ---------------------------------------------------------------------------
// K_att3 (MFMA): fused logits + softmax + gate + att0 -> attF (R15 exact).
// ---------------------------------------------------------------------------
__global__ __launch_bounds__(256) void k_att3(
    const unsigned short* __restrict__ pq, const unsigned short* __restrict__ pk,
    const float* __restrict__ inup_b, const float* __restrict__ graph,
    const float* __restrict__ att0, const float* __restrict__ red,
    const float* __restrict__ diff_w, const float* __restrict__ diff_b,
    unsigned short* __restrict__ attB) {
    const int n = blockIdx.x, s = blockIdx.y;
    const int tid = threadIdx.x;
    const int lane = tid & 63, wv = tid >> 6;
    const int r16 = lane & 15, g4 = lane >> 4;

    __shared__ unsigned short QS[25 * 536];
    __shared__ unsigned short KS[32 * 512];
    __shared__ float attL[80 * 33];
    __shared__ float gp4[8][4];
    __shared__ float g3[3];

    if (tid < 8) {
        const int oc = s * ICn + tid;
        float a = 0.f;
        for (int c = 0; c < Cn; ++c)
            a += red[(n * Cn + c) * 4 + 3] * diff_w[oc * Cn + c];
        gp4[tid][0] = a + 1600.f * diff_b[oc];
        gp4[tid][1] = red[(n * Cn + oc) * 4 + 0];
        gp4[tid][2] = red[(n * Cn + oc) * 4 + 1];
        gp4[tid][3] = red[(n * Cn + oc) * 4 + 2];
    }
    for (int i = tid; i < 2048; i += 256) {
        const int t = i & 63, v = i >> 6;
        s16x8 d = (s16x8){0, 0, 0, 0, 0, 0, 0, 0};
        if (v < Vn)
            d = *(const s16x8*)(pk + ((((size_t)(n * Sn + s) * Vn + v) * Tn + t) << 3));
        *(s16x8*)&KS[v * 512 + ((t ^ (v & 7)) << 3)] = d;
    }
    for (int i = tid; i < 1600; i += 256) {
        const int t = i & 63, uu = i >> 6;
        const s16x8 d = *(const s16x8*)(pq +
            ((((size_t)(n * Sn + s) * Vn + uu) * Tn + t) << 3));
        *(s16x8*)&QS[uu * 536 + (t + 1) * 8] = d;
    }
    if (tid < 50) {
        const int uu = tid >> 1, slot = (tid & 1) * 65;
#pragma unroll
        for (int cc = 0; cc < ICn; ++cc)
            QS[uu * 536 + slot * 8 + cc] = f2bf(inup_b[s * ICn + cc]);
    }
    __syncthreads();

    for (int tile = wv; tile < 10; tile += 4) {
        const int mt = tile >> 1, nt = tile & 1;
        const int u = mt * 16 + r16;
        const int w = u / 25, uu = u % 25;
        const int v = nt * 16 + r16;
        const unsigned short* qbase = &QS[uu * 536 + (g4 + w) * 8];
        const unsigned short* kbase = &KS[v * 512];
        f32x4 acc = (f32x4){0.f, 0.f, 0.f, 0.f};
#pragma unroll
        for (int kb = 0; kb < 16; ++kb) {
            const s16x8 af = *(const s16x8*)(qbase + kb * 32);
            const s16x8 bf = *(const s16x8*)(kbase + (((kb * 4 + g4) ^ (v & 7)) << 3));
            acc = MFMA16(af, bf, acc);
        }
#pragma unroll
        for (int r = 0; r < 4; ++r)
            attL[(mt * 16 + g4 * 4 + r) * 33 + v] = acc[r];
    }
    if (tid == 0) {
        float sumd2 = 0.f, rsum = 0.f, rr0 = 0.f, rr63 = 0.f;
#pragma unroll
        for (int cc = 0; cc < 8; ++cc) {
            sumd2 += gp4[cc][0]; rsum += gp4[cc][1];
            rr0 += gp4[cc][2]; rr63 += gp4[cc][3];
        }
        const float inv = 1.f / 12800.f;
        g3[0] = 1.f / (1.f + expf(-(sumd2 - (rsum - rr63)) * inv));
        g3[1] = 1.f / (1.f + expf(-(sumd2 - rsum) * inv));
        g3[2] = 1.f / (1.f + expf(-(sumd2 - (rsum - rr0)) * inv));
    }
    __syncthreads();

    if (tid < WVn) {
        const int u = tid, u0 = u % Vn;
        const float* gr = graph + (s * Vn + u0) * Vn;
        float av[Vn];
        float mx = -1e30f;
#pragma unroll
        for (int v = 0; v < Vn; ++v) {
            float a = attL[u * 33 + v] * (1.f / 512.f);
            av[v] = (gr[v] > 0.f) ? a : -1e30f;
            mx = fmaxf(mx, av[v]);
        }
        float ssum = 0.f;
#pragma unroll
        for (int v = 0; v < Vn; ++v) {
            float e = (av[v] > -1e29f) ? expf(av[v] - mx) : 0.f;
            av[v] = e;
            ssum += e;
        }
        const float sc = g3[u % Wn] / ssum;
        const float* a0 = att0 + (s * WVn + u) * Vn;
#pragma unroll
        for (int v = 0; v < Vn; ++v) attL[u * 33 + v] = av[v] * sc + a0[v];
    }
    __syncthreads();

    unsigned short* ab = attB + ((size_t)(n * Sn + s)) * 3072;
    for (int idx = tid; idx < 3072; idx += 256) {
        const int j = idx & 7, ln = (idx >> 3) & 63, f = idx >> 9;
        const int k = f >> 1, nt = f & 1;
        const int v = nt * 16 + (ln & 15);
        const int vp = (ln >> 4) * 8 + j;
        float val = (v < Vn && vp < Vn) ? attL[(k * Vn + vp) * 33 + v] : 0.f;
        ab[idx] = f2bf(val);
    }
}

// ---------------------------------------------------------------------------
// K_trans: x -> xT[n][t][c][v-swz] bf16 (byte-identical).
// ---------------------------------------------------------------------------
__global__ __launch_bounds__(256) void k_trans(const float* __restrict__ x,
                                               unsigned short* __restrict__ xT) {
    const int n = blockIdx.x, cb = blockIdx.y;
    const int c0 = cb * 4;
    const int tid = threadIdx.x;
    __shared__ unsigned short XL[4][25][66];

    for (int i = tid; i < 1600; i += 256) {
        const int piece = i & 15, row = i >> 4;
        const int cl = row / 25, v = row - cl * 25;
        const float4 d = *(const float4*)(x +
            ((size_t)((n * Cn + c0 + cl) * Vn + v)) * Tn + piece * 4);
        unsigned short* dst = &XL[cl][v][piece * 4];
        dst[0] = f2bf(d.x); dst[1] = f2bf(d.y); dst[2] = f2bf(d.z); dst[3] = f2bf(d.w);
    }
    __syncthreads();
    for (int j = tid; j < 1024; j += 256) {
        const int p = j & 3, cl = (j >> 2) & 3, t = j >> 4;
        const int v0 = (p ^ cl) * 8;
        unsigned short buf[8];
#pragma unroll
        for (int jj = 0; jj < 8; ++jj) {
            const int v = v0 + jj;
            buf[jj] = (v < Vn) ? XL[cl][v][t] : (unsigned short)0;
        }
        *(s16x8*)(xT + ((size_t)(n * Tn + t) * 2048) + (c0 + cl) * 32 + p * 8) =
            *(const s16x8*)buf;
    }
}

// ---------------------------------------------------------------------------
// K_main11 (fallback, R15-exact): block = one (n,t), direct scattered stores.
// ---------------------------------------------------------------------------
__global__ __launch_bounds__(256, 3) void k_main11(
    const unsigned short* __restrict__ xT, const unsigned short* __restrict__ attB,
    const unsigned short* __restrict__ out_wbf, const float* __restrict__ out_b,
    const float* __restrict__ og, const float* __restrict__ obeta,
    const float* __restrict__ orm, const float* __restrict__ orv,
    const unsigned short* __restrict__ ff_wbf, const float* __restrict__ ff_b,
    const float* __restrict__ fg, const float* __restrict__ fbeta,
    const float* __restrict__ frm, const float* __restrict__ frv,
    float* __restrict__ out) {
    const int n = blockIdx.x, t = blockIdx.y;
    const int tid = threadIdx.x;
    const int lane = tid & 63, wv = tid >> 6;
    const int r16 = lane & 15, g4 = lane >> 4;

    __shared__ unsigned short xs3[3 * 2048];
    __shared__ unsigned short y2L[32 * 512];
    __shared__ unsigned short y1L[32 * 64];
    __shared__ float bnp[384];

    if (tid < 64) {
        int o = tid;
        float so = og[o] * rsqrtf(orv[o] + 1e-5f);
        bnp[o] = so; bnp[64 + o] = obeta[o] - orm[o] * so; bnp[128 + o] = out_b[o];
        float sf = fg[o] * rsqrtf(frv[o] + 1e-5f);
        bnp[192 + o] = sf; bnp[256 + o] = fbeta[o] - frm[o] * sf; bnp[320 + o] = ff_b[o];
    }
    for (int ch = tid; ch < 768; ch += 256) {
        const int kb = ch >> 8, off = ch & 255;
        const int tg = t - 1 + kb;
        s16x8 d = (s16x8){0, 0, 0, 0, 0, 0, 0, 0};
        if (tg >= 0 && tg < Tn)
            d = *(const s16x8*)(xT + ((size_t)(n * Tn + tg) * 2048) + off * 8);
        *(s16x8*)&xs3[ch * 8] = d;
    }
    __syncthreads();

    s16x8 af[4][3];
#pragma unroll
    for (int m = 0; m < 4; ++m) {
        const int c = m * 16 + r16;
#pragma unroll
        for (int kb = 0; kb < 3; ++kb)
            af[m][kb] = *(const s16x8*)&xs3[kb * 2048 + c * 32 + ((g4 ^ (c & 3)) << 3)];
    }
#pragma unroll
    for (int si = 0; si < 2; ++si) {
        const int s = wv * 2 + si;
        const unsigned short* aB = attB + ((size_t)(n * Sn + s)) * 3072;
        s16x8 bfr[3][2];
#pragma unroll
        for (int k = 0; k < 3; ++k)
#pragma unroll
            for (int nt = 0; nt < 2; ++nt)
                bfr[k][nt] = *(const s16x8*)(aB + (((k * 2 + nt) * 64 + lane) << 3));
#pragma unroll
        for (int m = 0; m < 4; ++m) {
            f32x4 c0 = (f32x4){0.f, 0.f, 0.f, 0.f};
            f32x4 c1 = (f32x4){0.f, 0.f, 0.f, 0.f};
#pragma unroll
            for (int kb = 0; kb < 3; ++kb) {
                c0 = MFMA16(af[m][kb], bfr[kb][0], c0);
                c1 = MFMA16(af[m][kb], bfr[kb][1], c1);
            }
            const int cw = m * 16 + g4 * 4;
            s16x4 p0, p1;
#pragma unroll
            for (int r = 0; r < 4; ++r) { p0[r] = f2bf(c0[r]); p1[r] = f2bf(c1[r]); }
            const int v0 = r16, v1 = 16 + r16;
            *(s16x4*)&y2L[v0 * 512 + (s * 8 + ((cw >> 3) ^ (v0 & 7))) * 8 + (cw & 7)] = p0;
            *(s16x4*)&y2L[v1 * 512 + (s * 8 + ((cw >> 3) ^ (v1 & 7))) * 8 + (cw & 7)] = p1;
        }
    }
    __syncthreads();

    f32x4 accO[2];
    accO[0] = (f32x4){0.f, 0.f, 0.f, 0.f};
    accO[1] = (f32x4){0.f, 0.f, 0.f, 0.f};
#pragma unroll
    for (int ks = 0; ks < 16; ++ks) {
        const s16x8 wa = *(const s16x8*)(out_wbf +
            ((((size_t)(wv * 16 + ks)) * 64 + lane) << 3));
        const int cidx = ks * 4 + g4;
        const int srow = cidx >> 3, lc = cidx & 7;
#pragma unroll
        for (int na = 0; na < 2; ++na) {
            const int v = na * 16 + r16;
            const s16x8 b = *(const s16x8*)&y2L[v * 512 + (srow * 8 + (lc ^ (v & 7))) * 8];
            accO[na] = MFMA16(wa, b, accO[na]);
        }
    }
    float xvc[2][4];
    const int ob = wv * 16 + g4 * 4;
#pragma unroll
    for (int na = 0; na < 2; ++na) {
        const int v = na * 16 + r16;
        s16x4 p;
#pragma unroll
        for (int r = 0; r < 4; ++r) {
            const int o = ob + r;
            const float xv = bf2f(xs3[2048 + o * 32 + ((((v >> 3)) ^ (o & 3)) << 3) + (v & 7)]);
            xvc[na][r] = xv;
            float val = (accO[na][r] + bnp[128 + o]) * bnp[o] + bnp[64 + o];
            float y1 = xv + val;
            y1 = (y1 > 0.f) ? y1 : 0.1f * y1;
            p[r] = f2bf(y1);
        }
        *(s16x4*)&y1L[v * 64 + (((ob >> 3) ^ (v & 7)) << 3) + (ob & 7)] = p;
    }
    __syncthreads();

    f32x4 accF[2];
    accF[0] = (f32x4){0.f, 0.f, 0.f, 0.f};
    accF[1] = (f32x4){0.f, 0.f, 0.f, 0.f};
#pragma unroll
    for (int ks = 0; ks < 2; ++ks) {
        const s16x8 fa = *(const s16x8*)(ff_wbf + (((wv * 2 + ks) * 64 + lane) << 3));
        const int cidx = ks * 4 + g4;
#pragma unroll
        for (int na = 0; na < 2; ++na) {
            const int v = na * 16 + r16;
            const s16x8 b = *(const s16x8*)&y1L[v * 64 + ((cidx ^ (v & 7)) << 3)];
            accF[na] = MFMA16(fa, b, accF[na]);
        }
    }
#pragma unroll
    for (int na = 0; na < 2; ++na) {
        const int v = na * 16 + r16;
        if (v < Vn) {
#pragma unroll
            for (int r = 0; r < 4; ++r) {
                const int o = ob + r;
                const float xv = xvc[na][r];
                float val = (accF[na][r] + bnp[320 + o]) * bnp[192 + o] + bnp[256 + o];
                float y2v = xv + val;
                y2v = (y2v > 0.f) ? y2v : 0.1f * y2v;
                float outv = y2v + xv;
                outv = (outv > 0.f) ? outv : 0.f;
                out[((size_t)(n * Cn + o) * Vn + v) * Tn + t] = outv;
            }
        }
    }
}

// ---------------------------------------------------------------------------
// K_main13 (t-pair): block = (n, t-pair), 2048 blocks, 3/CU at 45.7 KB.
// Processes t0, t0+1 sequentially over shared y2L/y1L: xs staged once
// (4 rows), bfr/wa/fa re-reads within the block are L1/L2 hits.
// Barrier schedule per tl: [p1; B; p2+epi1; B; ff+epi2; (B before next p1)]
// -- y2L overwrite for tl=1 is safe: all waves finished p2(t0) reads at B2.
// ---------------------------------------------------------------------------
__global__ __launch_bounds__(256, 3) void k_main13(
    const unsigned short* __restrict__ xT, const unsigned short* __restrict__ attB,
    const unsigned short* __restrict__ out_wbf, const float* __restrict__ out_b,
    const float* __restrict__ og, const float* __restrict__ obeta,
    const float* __restrict__ orm, const float* __restrict__ orv,
    const unsigned short* __restrict__ ff_wbf, const float* __restrict__ ff_b,
    const float* __restrict__ fg, const float* __restrict__ fbeta,
    const float* __restrict__ frm, const float* __restrict__ frv,
    float* __restrict__ outT) {
    const int n = blockIdx.x, tp = blockIdx.y;
    const int t0 = tp * 2;
    const int tid = threadIdx.x;
    const int lane = tid & 63, wv = tid >> 6;
    const int r16 = lane & 15, g4 = lane >> 4;

    __shared__ unsigned short xs4[4 * 2048];   // rows t0-1 .. t0+2, 16 KB
    __shared__ unsigned short y2L[32 * 512];   // 32 KB
    __shared__ unsigned short y1L[32 * 64];    // 4 KB
    __shared__ float bnp[384];

    if (tid < 64) {
        int o = tid;
        float so = og[o] * rsqrtf(orv[o] + 1e-5f);
        bnp[o] = so; bnp[64 + o] = obeta[o] - orm[o] * so; bnp[128 + o] = out_b[o];
        float sf = fg[o] * rsqrtf(frv[o] + 1e-5f);
        bnp[192 + o] = sf; bnp[256 + o] = fbeta[o] - frm[o] * sf; bnp[320 + o] = ff_b[o];
    }
    // ---- stage 4 xT rows (1024 x 16B chunks, coalesced)
    for (int ch = tid; ch < 1024; ch += 256) {
        const int kb = ch >> 8, off = ch & 255;
        const int tg = t0 - 1 + kb;
        s16x8 d = (s16x8){0, 0, 0, 0, 0, 0, 0, 0};
        if (tg >= 0 && tg < Tn)
            d = *(const s16x8*)(xT + ((size_t)(n * Tn + tg) * 2048) + off * 8);
        *(s16x8*)&xs4[ch * 8] = d;
    }
    __syncthreads();

    const int ob = wv * 16 + g4 * 4;
#pragma unroll
    for (int tl = 0; tl < 2; ++tl) {
        const int t = t0 + tl;
        // ---- phase1: aggregation (wave-private s pair); af from xs4 rows tl..tl+2
        s16x8 af[4][3];
#pragma unroll
        for (int m = 0; m < 4; ++m) {
            const int c = m * 16 + r16;
#pragma unroll
            for (int kb = 0; kb < 3; ++kb)
                af[m][kb] = *(const s16x8*)&xs4[(tl + kb) * 2048 + c * 32 + ((g4 ^ (c & 3)) << 3)];
        }
#pragma unroll
        for (int si = 0; si < 2; ++si) {
            const int s = wv * 2 + si;
            const unsigned short* aB = attB + ((size_t)(n * Sn + s)) * 3072;
            s16x8 bfr[3][2];
#pragma unroll
            for (int k = 0; k < 3; ++k)
#pragma unroll
                for (int nt = 0; nt < 2; ++nt)
                    bfr[k][nt] = *(const s16x8*)(aB + (((k * 2 + nt) * 64 + lane) << 3));
#pragma unroll
            for (int m = 0; m < 4; ++m) {
                f32x4 c0 = (f32x4){0.f, 0.f, 0.f, 0.f};
                f32x4 c1 = (f32x4){0.f, 0.f, 0.f, 0.f};
#pragma unroll
                for (int kb = 0; kb < 3; ++kb) {
                    c0 = MFMA16(af[m][kb], bfr[kb][0], c0);
                    c1 = MFMA16(af[m][kb], bfr[kb][1], c1);
                }
                const int cw = m * 16 + g4 * 4;
                s16x4 p0, p1;
#pragma unroll
                for (int r = 0; r < 4; ++r) { p0[r] = f2bf(c0[r]); p1[r] = f2bf(c1[r]); }
                const int v0 = r16, v1 = 16 + r16;
                *(s16x4*)&y2L[v0 * 512 + (s * 8 + ((cw >> 3) ^ (v0 & 7))) * 8 + (cw & 7)] = p0;
                *(s16x4*)&y2L[v1 * 512 + (s * 8 + ((cw >> 3) ^ (v1 & 7))) * 8 + (cw & 7)] = p1;
            }
        }
        __syncthreads();   // B1: y2L ready

        // ---- phase2: out-proj GEMM K=512
        f32x4 accO[2];
        accO[0] = (f32x4){0.f, 0.f, 0.f, 0.f};
        accO[1] = (f32x4){0.f, 0.f, 0.f, 0.f};
#pragma unroll
        for (int ks = 0; ks < 16; ++ks) {
            const s16x8 wa = *(const s16x8*)(out_wbf +
                ((((size_t)(wv * 16 + ks)) * 64 + lane) << 3));
            const int cidx = ks * 4 + g4;
            const int srow = cidx >> 3, lc = cidx & 7;
#pragma unroll
            for (int na = 0; na < 2; ++na) {
                const int v = na * 16 + r16;
                const s16x8 b = *(const s16x8*)&y2L[v * 512 + (srow * 8 + (lc ^ (v & 7))) * 8];
                accO[na] = MFMA16(wa, b, accO[na]);
            }
        }
        // ---- epi1: y1 = leaky(x + BN(accO)) -> y1L; xv from xs4 row tl+1
        float xvc[2][4];
#pragma unroll
        for (int na = 0; na < 2; ++na) {
            const int v = na * 16 + r16;
            s16x4 p;
#pragma unroll
            for (int r = 0; r < 4; ++r) {
                const int o = ob + r;
                const float xv = bf2f(xs4[(tl + 1) * 2048 + o * 32 +
                                          ((((v >> 3)) ^ (o & 3)) << 3) + (v & 7)]);
                xvc[na][r] = xv;
                float val = (accO[na][r] + bnp[128 + o]) * bnp[o] + bnp[64 + o];
                float y1 = xv + val;
                y1 = (y1 > 0.f) ? y1 : 0.1f * y1;
                p[r] = f2bf(y1);
            }
            *(s16x4*)&y1L[v * 64 + (((ob >> 3) ^ (v & 7)) << 3) + (ob & 7)] = p;
        }
        __syncthreads();   // B2: y1L ready; all y2L reads done

        // ---- ff: K=64 GEMM
        f32x4 accF[2];
        accF[0] = (f32x4){0.f, 0.f, 0.f, 0.f};
        accF[1] = (f32x4){0.f, 0.f, 0.f, 0.f};
#pragma unroll
        for (int ks = 0; ks < 2; ++ks) {
            const s16x8 fa = *(const s16x8*)(ff_wbf + (((wv * 2 + ks) * 64 + lane) << 3));
            const int cidx = ks * 4 + g4;
#pragma unroll
            for (int na = 0; na < 2; ++na) {
                const int v = na * 16 + r16;
                const s16x8 b = *(const s16x8*)&y1L[v * 64 + ((cidx ^ (v & 7)) << 3)];
                accF[na] = MFMA16(fa, b, accF[na]);
            }
        }
        // ---- epi2 + float4 store to outT
#pragma unroll
        for (int na = 0; na < 2; ++na) {
            const int v = na * 16 + r16;
            if (v < Vn) {
                float4 pv;
                float* pvp = (float*)&pv;
#pragma unroll
                for (int r = 0; r < 4; ++r) {
                    const int o = ob + r;
                    const float xv = xvc[na][r];
                    float val = (accF[na][r] + bnp[320 + o]) * bnp[192 + o] + bnp[256 + o];
                    float y2v = xv + val;
                    y2v = (y2v > 0.f) ? y2v : 0.1f * y2v;
                    float outv = y2v + xv;
                    outv = (outv > 0.f) ? outv : 0.f;
                    pvp[r] = outv;
                }
                *(float4*)(outT + ((size_t)(n * Tn + t) * Vn + v) * 64 + ob) = pv;
            }
        }
        if (tl == 0) __syncthreads();   // B3: y1L reads done before next epi1 write
    }
}

// ---------------------------------------------------------------------------
// K_out: outT[n][t][v][o] -> out (N,C,V,T), float4-along-t stores.
// ---------------------------------------------------------------------------
__global__ __launch_bounds__(256) void k_out(const float* __restrict__ outT,
                                             float* __restrict__ out) {
    const int n = blockIdx.x, tc = blockIdx.y;
    const int t0 = tc * 4;
    const int tid = threadIdx.x;
    __shared__ float outL[4 * 1600];

#pragma unroll
    for (int tl = 0; tl < 4; ++tl) {
        const float* src = outT + ((size_t)(n * Tn + t0 + tl) * Vn) * 64;
        for (int i = tid; i < 1600; i += 256)
            outL[tl * 1600 + i] = src[i];
    }
    __syncthreads();
    for (int r = tid; r < 1600; r += 256) {
        const int v = r >> 6, o = r & 63;
        float4 pv;
        pv.x = outL[0 * 1600 + r];
        pv.y = outL[1 * 1600 + r];
        pv.z = outL[2 * 1600 + r];
        pv.w = outL[3 * 1600 + r];
        *(float4*)(out + ((size_t)(n * Cn + o) * Vn + v) * Tn + t0) = pv;
    }
}

// ---------------------------------------------------------------------------
extern "C" void kernel_launch(void* const* d_in, const int* in_sizes, int n_in,
                              void* d_out, int out_size, void* d_ws, size_t ws_size,
                              hipStream_t stream) {
    const float* x       = (const float*)d_in[0];
    const float* graph   = (const float*)d_in[1];
    const float* graph_a = (const float*)d_in[2];
    const float* in_w    = (const float*)d_in[3];
    const float* in_b    = (const float*)d_in[4];
    const float* inup_w  = (const float*)d_in[5];
    const float* inup_b  = (const float*)d_in[6];
    const float* diff_w  = (const float*)d_in[7];
    const float* diff_b  = (const float*)d_in[8];
    const float* att0    = (const float*)d_in[9];
    const float* out_w   = (const float*)d_in[10];
    const float* out_b   = (const float*)d_in[11];
    const float* og      = (const float*)d_in[12];
    const float* obeta   = (const float*)d_in[13];
    const float* orm     = (const float*)d_in[14];
    const float* orv     = (const float*)d_in[15];
    const float* ff_w    = (const float*)d_in[16];
    const float* ff_b    = (const float*)d_in[17];
    const float* fg      = (const float*)d_in[18];
    const float* fbeta   = (const float*)d_in[19];
    const float* frm     = (const float*)d_in[20];
    const float* frv     = (const float*)d_in[21];
    float* out = (float*)d_out;

    // ws layout (bytes): red@0 (64K) | attF@71,680 (3M) | owF@3,217,408
    //   | ffF@3,282,944 | pq@3,291,136 (13.1M) | pk@16,398,336 (13.1M)
    //   xT ALIASES pq/pk @3,291,136 (dead after k_att3; ends 20,068,352)
    //   outT@20,068,352 (26.2M; needs ws >= 46,282,752)
    char* wsb = (char*)d_ws;
    float* red_ws  = (float*)(wsb);
    unsigned short* attB = (unsigned short*)(wsb + 71680);
    unsigned short* owb  = (unsigned short*)(wsb + 3217408);
    unsigned short* fwb  = (unsigned short*)(wsb + 3282944);
    unsigned short* pq = (unsigned short*)(wsb + 3291136);
    unsigned short* pk = (unsigned short*)(wsb + 16398336);
    unsigned short* xT = (unsigned short*)(wsb + 3291136);
    float* outT = (float*)(wsb + 20068352);
    const bool big = ws_size >= (size_t)46282752;

    k_red<<<dim3(Cn, Nn), 64, 0, stream>>>(x, graph_a, out_w, ff_w, red_ws, owb, fwb);
    k_proj2<<<dim3(Nn, Vn), 256, 0, stream>>>(x, in_w, in_b, inup_w, inup_b, pk, pq);
    k_att3<<<dim3(Nn, Sn), 256, 0, stream>>>(pq, pk, inup_b, graph, att0,
                                             red_ws, diff_w, diff_b, attB);
    k_trans<<<dim3(Nn, 16), 256, 0, stream>>>(x, xT);
    if (big) {
        k_main13<<<dim3(Nn, Tn / 2), 256, 0, stream>>>(xT, attB, owb, out_b, og, obeta,
                                                       orm, orv, fwb, ff_b, fg, fbeta,
                                                       frm, frv, outT);
        k_out<<<dim3(Nn, Tn / 4), 256, 0, stream>>>(outT, out);
    } else {
        k_main11<<<dim3(Nn, Tn), 256, 0, stream>>>(xT, attB, owb, out_b, og, obeta,
                                                   orm, orv, fwb, ff_b, fg, fbeta,
                                                   frm, frv, out);
    }
}

// Round 19
// 104.618 us; speedup vs baseline: 1.0540x; 1.0540x over previous
//
#include <hip/hip_runtime.h>
#include <hip/hip_bf16.h>
#include <math.h>

#define Nn 64
#define Cn 64
#define Tn 64
#define Vn 25
#define Sn 8
#define ICn 8
#define Wn 3
#define WVn 75

typedef __attribute__((ext_vector_type(8))) short s16x8;   // 8 bf16 (4 VGPR)
typedef __attribute__((ext_vector_type(4))) short s16x4;   // 4 bf16 (2 VGPR)
typedef __attribute__((ext_vector_type(4))) float f32x4;   // MFMA acc

#define MFMA16(a, b, c) __builtin_amdgcn_mfma_f32_16x16x32_bf16(a, b, c, 0, 0, 0)

static __device__ inline unsigned short f2bf(float f) {
    __hip_bfloat16 h = __float2bfloat16(f);
    return *reinterpret_cast<unsigned short*>(&h);
}
static __device__ inline float bf2f(unsigned short u) {
    union { unsigned int i; float f; } x;
    x.i = ((unsigned int)u) << 16;
    return x.f;
}

// ---------------------------------------------------------------------------
// K_red (R15 version, 4096 blocks): per (n,c) reductions; n==0 blocks emit
// PRE-FRAGMENTED bf16 weights (owF/ffF) so k_main's wa/fa loads are
// base+lane*16B coalesced.
// ---------------------------------------------------------------------------
__global__ __launch_bounds__(64) void k_red(const float* __restrict__ x,
                                            const float* __restrict__ ga,
                                            const float* __restrict__ ow,
                                            const float* __restrict__ fw,
                                            float* __restrict__ red,
                                            unsigned short* __restrict__ owb,
                                            unsigned short* __restrict__ fwb) {
    const int c = blockIdx.x, n = blockIdx.y;
    const int lane = threadIdx.x;
    if (n == 0) {
        for (int j8 = 0; j8 < 8; ++j8) {
            const int q = c * 512 + j8 * 64 + lane;
            const int j = q & 7, ln = (q >> 3) & 63, fi = q >> 9;
            const int wvq = fi >> 4, ksq = fi & 15;
            owb[q] = f2bf(ow[(wvq * 16 + (ln & 15)) * 512 + ksq * 32 + (ln >> 4) * 8 + j]);
        }
        {
            const int q = c * 64 + lane;
            const int j = q & 7, ln = (q >> 3) & 63, fi = q >> 9;
            const int wvq = fi >> 1, ksq = fi & 1;
            fwb[q] = f2bf(fw[(wvq * 16 + (ln & 15)) * 64 + ksq * 32 + (ln >> 4) * 8 + j]);
        }
    }
    float rs = 0.f, r0 = 0.f, r63 = 0.f, xg = 0.f;
    if (lane < Vn) {
        const float* row = x + ((size_t)(n * Cn + c) * Vn + lane) * Tn;
        float g = 0.f;
        for (int j = 0; j < Vn; ++j) g += ga[lane * Vn + j];
        for (int t = 0; t < Tn; ++t) rs += row[t];
        r0 = row[0];
        r63 = row[Tn - 1];
        xg = rs * g;
    }
    for (int off = 32; off > 0; off >>= 1) {
        rs += __shfl_down(rs, off);
        r0 += __shfl_down(r0, off);
        r63 += __shfl_down(r63, off);
        xg += __shfl_down(xg, off);
    }
    if (lane == 0) {
        float* p = red + (size_t)(n * Cn + c) * 4;
        p[0] = rs; p[1] = r0; p[2] = r63; p[3] = xg;
    }
}

// ---------------------------------------------------------------------------
// K_proj2 (MFMA): q/k conv1x1 -> bf16, layout [n][s][v][t][cc8] (R15 exact).
// ---------------------------------------------------------------------------
__global__ __launch_bounds__(256) void k_proj2(
    const float* __restrict__ x,
    const float* __restrict__ in_w, const float* __restrict__ in_b,
    const float* __restrict__ inup_w, const float* __restrict__ inup_b,
    unsigned short* __restrict__ pk, unsigned short* __restrict__ pq) {
    const int n = blockIdx.x, v = blockIdx.y;
    const int tid = threadIdx.x;
    const int lane = tid & 63, wv = tid >> 6;
    const int r16 = lane & 15, g4 = lane >> 4;

    __shared__ unsigned short WL[128 * 64];
    __shared__ unsigned short XT[64 * 64];
    __shared__ unsigned short CL[64 * 128];
    __shared__ float bias[128];

    if (tid < 128) bias[tid] = (tid < 64) ? in_b[tid] : inup_b[tid - 64];

    for (int idx = tid; idx < 2048; idx += 256) {
        const int o2 = idx >> 4, c4 = idx & 15;
        const float4 d = (o2 < 64)
            ? *(const float4*)(in_w + o2 * 64 + c4 * 4)
            : *(const float4*)(inup_w + (o2 - 64) * 64 + c4 * 4);
        s16x4 p;
        p[0] = (short)f2bf(d.x); p[1] = (short)f2bf(d.y);
        p[2] = (short)f2bf(d.z); p[3] = (short)f2bf(d.w);
        const int ch = c4 >> 1;
        *(s16x4*)&WL[o2 * 64 + (((ch ^ (o2 & 7))) << 3) + (c4 & 1) * 4] = p;
    }
    for (int idx = tid; idx < 1024; idx += 256) {
        const int c = idx >> 4, t4 = idx & 15;
        const float4 d = *(const float4*)(x +
            ((size_t)((n * Cn + c) * Vn + v)) * Tn + t4 * 4);
        const float dv[4] = {d.x, d.y, d.z, d.w};
#pragma unroll
        for (int jj = 0; jj < 4; ++jj) {
            const int t = t4 * 4 + jj;
            XT[t * 64 + (((c >> 3) ^ (t & 7)) << 3) + (c & 7)] = f2bf(dv[jj]);
        }
    }
    __syncthreads();

#pragma unroll
    for (int mi = 0; mi < 2; ++mi) {
        const int mt = wv * 2 + mi;
        const int o2r = mt * 16 + r16;
#pragma unroll
        for (int nt2 = 0; nt2 < 4; ++nt2) {
            const int t = nt2 * 16 + r16;
            f32x4 acc = (f32x4){0.f, 0.f, 0.f, 0.f};
#pragma unroll
            for (int ks = 0; ks < 2; ++ks) {
                const int ch = ks * 4 + g4;
                const s16x8 a = *(const s16x8*)&WL[o2r * 64 + ((ch ^ (o2r & 7)) << 3)];
                const s16x8 b = *(const s16x8*)&XT[t * 64 + ((ch ^ (t & 7)) << 3)];
                acc = MFMA16(a, b, acc);
            }
            const int tcol = nt2 * 16 + r16;
            const int ob = mt * 16 + g4 * 4;
            s16x4 p;
#pragma unroll
            for (int r = 0; r < 4; ++r) p[r] = f2bf(acc[r] + bias[ob + r]);
            const int ch = ob >> 3;
            *(s16x4*)&CL[tcol * 128 + ((ch ^ (tcol & 7)) << 3) + (ob & 7)] = p;
        }
    }
    __syncthreads();

    for (int jj = tid; jj < 1024; jj += 256) {
        const int t = jj & 63, p = jj >> 6;
        const s16x8 d = *(const s16x8*)&CL[t * 128 + ((p ^ (t & 7)) << 3)];
        const int s8 = p & 7;
        unsigned short* dst = (p < 8) ? pk : pq;
        *(s16x8*)(dst + ((((size_t)(n * Sn + s8) * Vn + v) * Tn + t) << 3)) = d;
    }
}

// ---------------------------------------------------------------------------
// K_att3 (MFMA): fused logits + softmax + gate + att0 -> attF (R15 exact).
// ---------------------------------------------------------------------------
__global__ __launch_bounds__(256) void k_att3(
    const unsigned short* __restrict__ pq, const unsigned short* __restrict__ pk,
    const float* __restrict__ inup_b, const float* __restrict__ graph,
    const float* __restrict__ att0, const float* __restrict__ red,
    const float* __restrict__ diff_w, const float* __restrict__ diff_b,
    unsigned short* __restrict__ attB) {
    const int n = blockIdx.x, s = blockIdx.y;
    const int tid = threadIdx.x;
    const int lane = tid & 63, wv = tid >> 6;
    const int r16 = lane & 15, g4 = lane >> 4;

    __shared__ unsigned short QS[25 * 536];
    __shared__ unsigned short KS[32 * 512];
    __shared__ float attL[80 * 33];
    __shared__ float gp4[8][4];
    __shared__ float g3[3];

    if (tid < 8) {
        const int oc = s * ICn + tid;
        float a = 0.f;
        for (int c = 0; c < Cn; ++c)
            a += red[(n * Cn + c) * 4 + 3] * diff_w[oc * Cn + c];
        gp4[tid][0] = a + 1600.f * diff_b[oc];
        gp4[tid][1] = red[(n * Cn + oc) * 4 + 0];
        gp4[tid][2] = red[(n * Cn + oc) * 4 + 1];
        gp4[tid][3] = red[(n * Cn + oc) * 4 + 2];
    }
    for (int i = tid; i < 2048; i += 256) {
        const int t = i & 63, v = i >> 6;
        s16x8 d = (s16x8){0, 0, 0, 0, 0, 0, 0, 0};
        if (v < Vn)
            d = *(const s16x8*)(pk + ((((size_t)(n * Sn + s) * Vn + v) * Tn + t) << 3));
        *(s16x8*)&KS[v * 512 + ((t ^ (v & 7)) << 3)] = d;
    }
    for (int i = tid; i < 1600; i += 256) {
        const int t = i & 63, uu = i >> 6;
        const s16x8 d = *(const s16x8*)(pq +
            ((((size_t)(n * Sn + s) * Vn + uu) * Tn + t) << 3));
        *(s16x8*)&QS[uu * 536 + (t + 1) * 8] = d;
    }
    if (tid < 50) {
        const int uu = tid >> 1, slot = (tid & 1) * 65;
#pragma unroll
        for (int cc = 0; cc < ICn; ++cc)
            QS[uu * 536 + slot * 8 + cc] = f2bf(inup_b[s * ICn + cc]);
    }
    __syncthreads();

    for (int tile = wv; tile < 10; tile += 4) {
        const int mt = tile >> 1, nt = tile & 1;
        const int u = mt * 16 + r16;
        const int w = u / 25, uu = u % 25;
        const int v = nt * 16 + r16;
        const unsigned short* qbase = &QS[uu * 536 + (g4 + w) * 8];
        const unsigned short* kbase = &KS[v * 512];
        f32x4 acc = (f32x4){0.f, 0.f, 0.f, 0.f};
#pragma unroll
        for (int kb = 0; kb < 16; ++kb) {
            const s16x8 af = *(const s16x8*)(qbase + kb * 32);
            const s16x8 bf = *(const s16x8*)(kbase + (((kb * 4 + g4) ^ (v & 7)) << 3));
            acc = MFMA16(af, bf, acc);
        }
#pragma unroll
        for (int r = 0; r < 4; ++r)
            attL[(mt * 16 + g4 * 4 + r) * 33 + v] = acc[r];
    }
    if (tid == 0) {
        float sumd2 = 0.f, rsum = 0.f, rr0 = 0.f, rr63 = 0.f;
#pragma unroll
        for (int cc = 0; cc < 8; ++cc) {
            sumd2 += gp4[cc][0]; rsum += gp4[cc][1];
            rr0 += gp4[cc][2]; rr63 += gp4[cc][3];
        }
        const float inv = 1.f / 12800.f;
        g3[0] = 1.f / (1.f + expf(-(sumd2 - (rsum - rr63)) * inv));
        g3[1] = 1.f / (1.f + expf(-(sumd2 - rsum) * inv));
        g3[2] = 1.f / (1.f + expf(-(sumd2 - (rsum - rr0)) * inv));
    }
    __syncthreads();

    if (tid < WVn) {
        const int u = tid, u0 = u % Vn;
        const float* gr = graph + (s * Vn + u0) * Vn;
        float av[Vn];
        float mx = -1e30f;
#pragma unroll
        for (int v = 0; v < Vn; ++v) {
            float a = attL[u * 33 + v] * (1.f / 512.f);
            av[v] = (gr[v] > 0.f) ? a : -1e30f;
            mx = fmaxf(mx, av[v]);
        }
        float ssum = 0.f;
#pragma unroll
        for (int v = 0; v < Vn; ++v) {
            float e = (av[v] > -1e29f) ? expf(av[v] - mx) : 0.f;
            av[v] = e;
            ssum += e;
        }
        const float sc = g3[u % Wn] / ssum;
        const float* a0 = att0 + (s * WVn + u) * Vn;
#pragma unroll
        for (int v = 0; v < Vn; ++v) attL[u * 33 + v] = av[v] * sc + a0[v];
    }
    __syncthreads();

    unsigned short* ab = attB + ((size_t)(n * Sn + s)) * 3072;
    for (int idx = tid; idx < 3072; idx += 256) {
        const int j = idx & 7, ln = (idx >> 3) & 63, f = idx >> 9;
        const int k = f >> 1, nt = f & 1;
        const int v = nt * 16 + (ln & 15);
        const int vp = (ln >> 4) * 8 + j;
        float val = (v < Vn && vp < Vn) ? attL[(k * Vn + vp) * 33 + v] : 0.f;
        ab[idx] = f2bf(val);
    }
}

// ---------------------------------------------------------------------------
// K_trans: x -> xT[n][t][c][v-swz] bf16 (byte-identical).
// ---------------------------------------------------------------------------
__global__ __launch_bounds__(256) void k_trans(const float* __restrict__ x,
                                               unsigned short* __restrict__ xT) {
    const int n = blockIdx.x, cb = blockIdx.y;
    const int c0 = cb * 4;
    const int tid = threadIdx.x;
    __shared__ unsigned short XL[4][25][66];

    for (int i = tid; i < 1600; i += 256) {
        const int piece = i & 15, row = i >> 4;
        const int cl = row / 25, v = row - cl * 25;
        const float4 d = *(const float4*)(x +
            ((size_t)((n * Cn + c0 + cl) * Vn + v)) * Tn + piece * 4);
        unsigned short* dst = &XL[cl][v][piece * 4];
        dst[0] = f2bf(d.x); dst[1] = f2bf(d.y); dst[2] = f2bf(d.z); dst[3] = f2bf(d.w);
    }
    __syncthreads();
    for (int j = tid; j < 1024; j += 256) {
        const int p = j & 3, cl = (j >> 2) & 3, t = j >> 4;
        const int v0 = (p ^ cl) * 8;
        unsigned short buf[8];
#pragma unroll
        for (int jj = 0; jj < 8; ++jj) {
            const int v = v0 + jj;
            buf[jj] = (v < Vn) ? XL[cl][v][t] : (unsigned short)0;
        }
        *(s16x8*)(xT + ((size_t)(n * Tn + t) * 2048) + (c0 + cl) * 32 + p * 8) =
            *(const s16x8*)buf;
    }
}

// ---------------------------------------------------------------------------
// k_main core shared by both variants. STORE_T selects the epilogue2 target:
// 0 = direct scattered stores to out (R15 behavior), 1 = float4 to outT.
// ---------------------------------------------------------------------------
template <int STORE_T>
static __device__ void main_core(
    const unsigned short* __restrict__ xT, const unsigned short* __restrict__ attB,
    const unsigned short* __restrict__ out_wbf, const float* __restrict__ out_b,
    const float* __restrict__ og, const float* __restrict__ obeta,
    const float* __restrict__ orm, const float* __restrict__ orv,
    const unsigned short* __restrict__ ff_wbf, const float* __restrict__ ff_b,
    const float* __restrict__ fg, const float* __restrict__ fbeta,
    const float* __restrict__ frm, const float* __restrict__ frv,
    float* __restrict__ out, float* __restrict__ outT) {
    const int n = blockIdx.x, t = blockIdx.y;
    const int tid = threadIdx.x;
    const int lane = tid & 63, wv = tid >> 6;
    const int r16 = lane & 15, g4 = lane >> 4;

    __shared__ unsigned short xs3[3 * 2048];
    __shared__ unsigned short y2L[32 * 512];
    __shared__ unsigned short y1L[32 * 64];
    __shared__ float bnp[384];

    if (tid < 64) {
        int o = tid;
        float so = og[o] * rsqrtf(orv[o] + 1e-5f);
        bnp[o] = so; bnp[64 + o] = obeta[o] - orm[o] * so; bnp[128 + o] = out_b[o];
        float sf = fg[o] * rsqrtf(frv[o] + 1e-5f);
        bnp[192 + o] = sf; bnp[256 + o] = fbeta[o] - frm[o] * sf; bnp[320 + o] = ff_b[o];
    }
    for (int ch = tid; ch < 768; ch += 256) {
        const int kb = ch >> 8, off = ch & 255;
        const int tg = t - 1 + kb;
        s16x8 d = (s16x8){0, 0, 0, 0, 0, 0, 0, 0};
        if (tg >= 0 && tg < Tn)
            d = *(const s16x8*)(xT + ((size_t)(n * Tn + tg) * 2048) + off * 8);
        *(s16x8*)&xs3[ch * 8] = d;
    }
    __syncthreads();

    s16x8 af[4][3];
#pragma unroll
    for (int m = 0; m < 4; ++m) {
        const int c = m * 16 + r16;
#pragma unroll
        for (int kb = 0; kb < 3; ++kb)
            af[m][kb] = *(const s16x8*)&xs3[kb * 2048 + c * 32 + ((g4 ^ (c & 3)) << 3)];
    }
#pragma unroll
    for (int si = 0; si < 2; ++si) {
        const int s = wv * 2 + si;
        const unsigned short* aB = attB + ((size_t)(n * Sn + s)) * 3072;
        s16x8 bfr[3][2];
#pragma unroll
        for (int k = 0; k < 3; ++k)
#pragma unroll
            for (int nt = 0; nt < 2; ++nt)
                bfr[k][nt] = *(const s16x8*)(aB + (((k * 2 + nt) * 64 + lane) << 3));
#pragma unroll
        for (int m = 0; m < 4; ++m) {
            f32x4 c0 = (f32x4){0.f, 0.f, 0.f, 0.f};
            f32x4 c1 = (f32x4){0.f, 0.f, 0.f, 0.f};
#pragma unroll
            for (int kb = 0; kb < 3; ++kb) {
                c0 = MFMA16(af[m][kb], bfr[kb][0], c0);
                c1 = MFMA16(af[m][kb], bfr[kb][1], c1);
            }
            const int cw = m * 16 + g4 * 4;
            s16x4 p0, p1;
#pragma unroll
            for (int r = 0; r < 4; ++r) { p0[r] = f2bf(c0[r]); p1[r] = f2bf(c1[r]); }
            const int v0 = r16, v1 = 16 + r16;
            *(s16x4*)&y2L[v0 * 512 + (s * 8 + ((cw >> 3) ^ (v0 & 7))) * 8 + (cw & 7)] = p0;
            *(s16x4*)&y2L[v1 * 512 + (s * 8 + ((cw >> 3) ^ (v1 & 7))) * 8 + (cw & 7)] = p1;
        }
    }
    __syncthreads();

    f32x4 accO[2];
    accO[0] = (f32x4){0.f, 0.f, 0.f, 0.f};
    accO[1] = (f32x4){0.f, 0.f, 0.f, 0.f};
#pragma unroll
    for (int ks = 0; ks < 16; ++ks) {
        const s16x8 wa = *(const s16x8*)(out_wbf +
            ((((size_t)(wv * 16 + ks)) * 64 + lane) << 3));
        const int cidx = ks * 4 + g4;
        const int srow = cidx >> 3, lc = cidx & 7;
#pragma unroll
        for (int na = 0; na < 2; ++na) {
            const int v = na * 16 + r16;
            const s16x8 b = *(const s16x8*)&y2L[v * 512 + (srow * 8 + (lc ^ (v & 7))) * 8];
            accO[na] = MFMA16(wa, b, accO[na]);
        }
    }
    float xvc[2][4];
    const int ob = wv * 16 + g4 * 4;
#pragma unroll
    for (int na = 0; na < 2; ++na) {
        const int v = na * 16 + r16;
        s16x4 p;
#pragma unroll
        for (int r = 0; r < 4; ++r) {
            const int o = ob + r;
            const float xv = bf2f(xs3[2048 + o * 32 + ((((v >> 3)) ^ (o & 3)) << 3) + (v & 7)]);
            xvc[na][r] = xv;
            float val = (accO[na][r] + bnp[128 + o]) * bnp[o] + bnp[64 + o];
            float y1 = xv + val;
            y1 = (y1 > 0.f) ? y1 : 0.1f * y1;
            p[r] = f2bf(y1);
        }
        *(s16x4*)&y1L[v * 64 + (((ob >> 3) ^ (v & 7)) << 3) + (ob & 7)] = p;
    }
    __syncthreads();

    f32x4 accF[2];
    accF[0] = (f32x4){0.f, 0.f, 0.f, 0.f};
    accF[1] = (f32x4){0.f, 0.f, 0.f, 0.f};
#pragma unroll
    for (int ks = 0; ks < 2; ++ks) {
        const s16x8 fa = *(const s16x8*)(ff_wbf + (((wv * 2 + ks) * 64 + lane) << 3));
        const int cidx = ks * 4 + g4;
#pragma unroll
        for (int na = 0; na < 2; ++na) {
            const int v = na * 16 + r16;
            const s16x8 b = *(const s16x8*)&y1L[v * 64 + ((cidx ^ (v & 7)) << 3)];
            accF[na] = MFMA16(fa, b, accF[na]);
        }
    }
#pragma unroll
    for (int na = 0; na < 2; ++na) {
        const int v = na * 16 + r16;
        if (v < Vn) {
            float4 pv;
            float* pvp = (float*)&pv;
#pragma unroll
            for (int r = 0; r < 4; ++r) {
                const int o = ob + r;
                const float xv = xvc[na][r];
                float val = (accF[na][r] + bnp[320 + o]) * bnp[192 + o] + bnp[256 + o];
                float y2v = xv + val;
                y2v = (y2v > 0.f) ? y2v : 0.1f * y2v;
                float outv = y2v + xv;
                outv = (outv > 0.f) ? outv : 0.f;
                if (STORE_T) pvp[r] = outv;
                else out[((size_t)(n * Cn + o) * Vn + v) * Tn + t] = outv;
            }
            if (STORE_T)
                *(float4*)(outT + ((size_t)(n * Tn + t) * Vn + v) * 64 + ob) = pv;
        }
    }
}

__global__ __launch_bounds__(256, 3) void k_main11(
    const unsigned short* __restrict__ xT, const unsigned short* __restrict__ attB,
    const unsigned short* __restrict__ out_wbf, const float* __restrict__ out_b,
    const float* __restrict__ og, const float* __restrict__ obeta,
    const float* __restrict__ orm, const float* __restrict__ orv,
    const unsigned short* __restrict__ ff_wbf, const float* __restrict__ ff_b,
    const float* __restrict__ fg, const float* __restrict__ fbeta,
    const float* __restrict__ frm, const float* __restrict__ frv,
    float* __restrict__ out) {
    main_core<0>(xT, attB, out_wbf, out_b, og, obeta, orm, orv, ff_wbf, ff_b,
                 fg, fbeta, frm, frv, out, nullptr);
}

__global__ __launch_bounds__(256, 3) void k_main12(
    const unsigned short* __restrict__ xT, const unsigned short* __restrict__ attB,
    const unsigned short* __restrict__ out_wbf, const float* __restrict__ out_b,
    const float* __restrict__ og, const float* __restrict__ obeta,
    const float* __restrict__ orm, const float* __restrict__ orv,
    const unsigned short* __restrict__ ff_wbf, const float* __restrict__ ff_b,
    const float* __restrict__ fg, const float* __restrict__ fbeta,
    const float* __restrict__ frm, const float* __restrict__ frv,
    float* __restrict__ outT) {
    main_core<1>(xT, attB, out_wbf, out_b, og, obeta, orm, orv, ff_wbf, ff_b,
                 fg, fbeta, frm, frv, nullptr, outT);
}

// ---------------------------------------------------------------------------
// K_out: outT[n][t][v][o] (contiguous 1600-float slabs per t) -> out (N,C,V,T)
// with float4-along-t stores. Block (n, tc of 4 t), 25.6 KB LDS.
// ---------------------------------------------------------------------------
__global__ __launch_bounds__(256) void k_out(const float* __restrict__ outT,
                                             float* __restrict__ out) {
    const int n = blockIdx.x, tc = blockIdx.y;
    const int t0 = tc * 4;
    const int tid = threadIdx.x;
    __shared__ float outL[4 * 1600];

#pragma unroll
    for (int tl = 0; tl < 4; ++tl) {
        const float* src = outT + ((size_t)(n * Tn + t0 + tl) * Vn) * 64;
        for (int i = tid; i < 1600; i += 256)
            outL[tl * 1600 + i] = src[i];
    }
    __syncthreads();
    for (int r = tid; r < 1600; r += 256) {
        const int v = r >> 6, o = r & 63;   // r = v*64+o
        float4 pv;
        pv.x = outL[0 * 1600 + r];
        pv.y = outL[1 * 1600 + r];
        pv.z = outL[2 * 1600 + r];
        pv.w = outL[3 * 1600 + r];
        *(float4*)(out + ((size_t)(n * Cn + o) * Vn + v) * Tn + t0) = pv;
    }
}

// ---------------------------------------------------------------------------
extern "C" void kernel_launch(void* const* d_in, const int* in_sizes, int n_in,
                              void* d_out, int out_size, void* d_ws, size_t ws_size,
                              hipStream_t stream) {
    const float* x       = (const float*)d_in[0];
    const float* graph   = (const float*)d_in[1];
    const float* graph_a = (const float*)d_in[2];
    const float* in_w    = (const float*)d_in[3];
    const float* in_b    = (const float*)d_in[4];
    const float* inup_w  = (const float*)d_in[5];
    const float* inup_b  = (const float*)d_in[6];
    const float* diff_w  = (const float*)d_in[7];
    const float* diff_b  = (const float*)d_in[8];
    const float* att0    = (const float*)d_in[9];
    const float* out_w   = (const float*)d_in[10];
    const float* out_b   = (const float*)d_in[11];
    const float* og      = (const float*)d_in[12];
    const float* obeta   = (const float*)d_in[13];
    const float* orm     = (const float*)d_in[14];
    const float* orv     = (const float*)d_in[15];
    const float* ff_w    = (const float*)d_in[16];
    const float* ff_b    = (const float*)d_in[17];
    const float* fg      = (const float*)d_in[18];
    const float* fbeta   = (const float*)d_in[19];
    const float* frm     = (const float*)d_in[20];
    const float* frv     = (const float*)d_in[21];
    float* out = (float*)d_out;

    // ws layout (bytes): red@0 (64K) | attF@71,680 (3M) | owF@3,217,408
    //   | ffF@3,282,944 | pq@3,291,136 (13.1M) | pk@16,398,336 (13.1M)
    //   xT ALIASES pq/pk @3,291,136 (16.7M, dead after k_att3; ends 20,068,352)
    //   outT@20,068,352 (26.2M, overlays dead pk tail; needs ws >= 46,282,752)
    char* wsb = (char*)d_ws;
    float* red_ws  = (float*)(wsb);
    unsigned short* attB = (unsigned short*)(wsb + 71680);
    unsigned short* owb  = (unsigned short*)(wsb + 3217408);
    unsigned short* fwb  = (unsigned short*)(wsb + 3282944);
    unsigned short* pq = (unsigned short*)(wsb + 3291136);
    unsigned short* pk = (unsigned short*)(wsb + 16398336);
    unsigned short* xT = (unsigned short*)(wsb + 3291136);
    float* outT = (float*)(wsb + 20068352);
    const bool big = ws_size >= (size_t)46282752;

    k_red<<<dim3(Cn, Nn), 64, 0, stream>>>(x, graph_a, out_w, ff_w, red_ws, owb, fwb);
    k_proj2<<<dim3(Nn, Vn), 256, 0, stream>>>(x, in_w, in_b, inup_w, inup_b, pk, pq);
    k_att3<<<dim3(Nn, Sn), 256, 0, stream>>>(pq, pk, inup_b, graph, att0,
                                             red_ws, diff_w, diff_b, attB);
    k_trans<<<dim3(Nn, 16), 256, 0, stream>>>(x, xT);
    if (big) {
        k_main12<<<dim3(Nn, Tn), 256, 0, stream>>>(xT, attB, owb, out_b, og, obeta,
                                                   orm, orv, fwb, ff_b, fg, fbeta,
                                                   frm, frv, outT);
        k_out<<<dim3(Nn, Tn / 4), 256, 0, stream>>>(outT, out);
    } else {
        k_main11<<<dim3(Nn, Tn), 256, 0, stream>>>(xT, attB, owb, out_b, og, obeta,
                                                   orm, orv, fwb, ff_b, fg, fbeta,
                                                   frm, frv, out);
    }
}